// Round 3
// baseline (3997.351 us; speedup 1.0000x reference)
//
#include <hip/hip_runtime.h>
#include <math.h>

// Problem constants
#define NR   16384
#define EMB  4096
#define DD1  512
#define DD2  256
#define DIM  32
#define NQ   3
#define CBN  7000

typedef unsigned long long u64;

// ws layout (float offsets). bufA hosts h1 then dec-h2; bufB hosts h2 then dec-h1.
#define OFF_A    0ull          // 16384*512  = 8388608
#define OFF_B    8388608ull    // 16384*256  = 4194304
#define OFF_Z    12582912ull   // 16384*32   = 524288
#define OFF_Q    13107200ull   // 16384*32   = 524288
#define OFF_CN   13631488ull   // 3*7000     = 21000
#define OFF_LOSS 13652488ull   // 4
// total ~54.6 MB of ws

// d_out layout (floats): [out 16384*4096][indices 16384*3 as float][loss 3]
#define OUT_ELEMS 67108864ull
#define IDX_OFF   67108864ull
#define LOSS_OFF  67158016ull

// ---------------- classic f32 SGEMM: 128x128 tile, BK=8, 8x8 per thread ----------------
template<bool RELU>
__global__ __launch_bounds__(256) void sgemm128(const float* __restrict__ A,
    const float* __restrict__ B, const float* __restrict__ bias,
    float* __restrict__ C, int M, int N, int K)
{
  __shared__ float As[8][128];
  __shared__ float Bs[8][128];
  const int t  = threadIdx.x;
  const int tx = t & 15, ty = t >> 4;
  const int colBase = blockIdx.x * 128 + tx * 8;
  const int rowBase = blockIdx.y * 128 + ty * 8;

  float acc[8][8];
  #pragma unroll
  for (int i = 0; i < 8; ++i)
    #pragma unroll
    for (int j = 0; j < 8; ++j) acc[i][j] = 0.f;

  const int ar = t >> 1;          // 0..127 tile row of A
  const int ac = (t & 1) * 4;     // k-offset 0 or 4
  const int br = t >> 5;          // 0..7 k row of B
  const int bc = (t & 31) * 4;    // col offset
  const float* Ap = A + (u64)(blockIdx.y * 128 + ar) * K + ac;
  const float* Bp = B + (u64)br * N + blockIdx.x * 128 + bc;

  for (int k0 = 0; k0 < K; k0 += 8) {
    float4 av = *(const float4*)(Ap + k0);
    float4 bv = *(const float4*)(Bp + (u64)k0 * N);
    As[ac + 0][ar] = av.x; As[ac + 1][ar] = av.y;
    As[ac + 2][ar] = av.z; As[ac + 3][ar] = av.w;
    *(float4*)&Bs[br][bc] = bv;
    __syncthreads();
    #pragma unroll
    for (int k = 0; k < 8; ++k) {
      float4 a0 = *(const float4*)&As[k][ty * 8];
      float4 a1 = *(const float4*)&As[k][ty * 8 + 4];
      float4 b0 = *(const float4*)&Bs[k][tx * 8];
      float4 b1 = *(const float4*)&Bs[k][tx * 8 + 4];
      float ra[8] = {a0.x, a0.y, a0.z, a0.w, a1.x, a1.y, a1.z, a1.w};
      float rb[8] = {b0.x, b0.y, b0.z, b0.w, b1.x, b1.y, b1.z, b1.w};
      #pragma unroll
      for (int i = 0; i < 8; ++i)
        #pragma unroll
        for (int j = 0; j < 8; ++j)
          acc[i][j] = fmaf(ra[i], rb[j], acc[i][j]);
    }
    __syncthreads();
  }

  float bvs[8];
  #pragma unroll
  for (int j = 0; j < 8; ++j) bvs[j] = bias[colBase + j];
  #pragma unroll
  for (int i = 0; i < 8; ++i) {
    float o[8];
    #pragma unroll
    for (int j = 0; j < 8; ++j) {
      float v = acc[i][j] + bvs[j];
      if (RELU) v = v > 0.f ? v : 0.f;
      o[j] = v;
    }
    float* cp = C + (u64)(rowBase + i) * N + colBase;
    *(float4*)cp       = make_float4(o[0], o[1], o[2], o[3]);
    *(float4*)(cp + 4) = make_float4(o[4], o[5], o[6], o[7]);
  }
}

// ---------------- enc2: [16384,256] @ [256,32] + b (no relu) ----------------
__global__ __launch_bounds__(256) void enc2_kernel(const float* __restrict__ H,
    const float* __restrict__ W, const float* __restrict__ b, float* __restrict__ Z)
{
  __shared__ float Ws[DD2 * DIM];   // 32 KB
  __shared__ float bs[DIM];
  for (int i = threadIdx.x; i < DD2 * DIM; i += 256) Ws[i] = W[i];
  if (threadIdx.x < DIM) bs[threadIdx.x] = b[threadIdx.x];
  __syncthreads();
  const int c    = threadIdx.x & 31;
  const int rloc = threadIdx.x >> 5;   // 0..7
  const int base = blockIdx.x * 64;
  for (int r0 = 0; r0 < 64; r0 += 8) {
    const int row = base + r0 + rloc;
    const float* h = H + (u64)row * DD2;
    float acc = bs[c];
    #pragma unroll 8
    for (int k = 0; k < DD2; ++k) acc = fmaf(h[k], Ws[k * DIM + c], acc);
    Z[(u64)row * DIM + c] = acc;
  }
}

// ---------------- codebook squared norms ----------------
__global__ __launch_bounds__(256) void cnorm_kernel(const float* __restrict__ cbk,
                                                    float* __restrict__ cn)
{
  int i = blockIdx.x * 256 + threadIdx.x;
  if (i < NQ * CBN) {
    const float* c = cbk + (u64)i * DIM;
    float s = 0.f;
    #pragma unroll
    for (int k = 0; k < DIM; ++k) s = fmaf(c[k], c[k], s);
    cn[i] = s;
  }
}

// ---------------- residual VQ: 64 rows/block, argmin over 7000 cbs x 3 quantizers ----------------
__global__ __launch_bounds__(256) void vq_kernel(const float* __restrict__ Z,
    const float* __restrict__ CBK, const float* __restrict__ CN,
    float* __restrict__ Qout, float* __restrict__ lossAcc, float* __restrict__ idxOut)
{
  __shared__ float zs[64][DIM];
  __shared__ float rs[64][36];     // pad to 36 keeps float4 alignment (144 B rows)
  __shared__ float cb[64][36];
  __shared__ float cn[64];
  __shared__ float redv[64][16];
  __shared__ int   redi[64][16];
  __shared__ int   bidx[64];
  __shared__ float lred[256];

  const int t = threadIdx.x;
  const int rowBase = blockIdx.x * 64;
  for (int i = t; i < 64 * DIM; i += 256) {
    float v = Z[(u64)rowBase * DIM + i];
    zs[i >> 5][i & 31] = v;
    rs[i >> 5][i & 31] = v;
  }
  __syncthreads();

  const int tx = t & 15, ty = t >> 4;

  for (int q = 0; q < NQ; ++q) {
    float minv[4] = {1e30f, 1e30f, 1e30f, 1e30f};
    int   mini[4] = {0, 0, 0, 0};

    for (int jt = 0; jt < 110; ++jt) {
      const int jbase = jt * 64;
      for (int i = t; i < 64 * DIM; i += 256) {
        int j = jbase + (i >> 5);
        cb[i >> 5][i & 31] = (j < CBN) ? CBK[((u64)q * CBN + j) * DIM + (i & 31)] : 0.f;
      }
      if (t < 64) {
        int j = jbase + t;
        cn[t] = (j < CBN) ? CN[q * CBN + j] : 1e30f;
      }
      __syncthreads();

      float acc[4][4];
      #pragma unroll
      for (int i = 0; i < 4; ++i)
        #pragma unroll
        for (int j = 0; j < 4; ++j) acc[i][j] = 0.f;

      #pragma unroll
      for (int k4 = 0; k4 < DIM; k4 += 4) {
        float4 ra[4], rc[4];
        #pragma unroll
        for (int u = 0; u < 4; ++u) ra[u] = *(const float4*)&rs[ty * 4 + u][k4];
        #pragma unroll
        for (int u = 0; u < 4; ++u) rc[u] = *(const float4*)&cb[tx * 4 + u][k4];
        #pragma unroll
        for (int i = 0; i < 4; ++i)
          #pragma unroll
          for (int j = 0; j < 4; ++j)
            acc[i][j] += ra[i].x * rc[j].x + ra[i].y * rc[j].y
                       + ra[i].z * rc[j].z + ra[i].w * rc[j].w;
      }
      #pragma unroll
      for (int j = 0; j < 4; ++j) {
        const int col = jbase + tx * 4 + j;
        const float cnj = cn[tx * 4 + j];
        #pragma unroll
        for (int i = 0; i < 4; ++i) {
          float d = cnj - 2.f * acc[i][j];
          if (d < minv[i]) { minv[i] = d; mini[i] = col; }  // strict < keeps smallest idx
        }
      }
      __syncthreads();
    }

    #pragma unroll
    for (int i = 0; i < 4; ++i) { redv[ty * 4 + i][tx] = minv[i]; redi[ty * 4 + i][tx] = mini[i]; }
    __syncthreads();
    if (t < 64) {
      float bv = redv[t][0]; int bi = redi[t][0];
      for (int x = 1; x < 16; ++x) {
        float v = redv[t][x]; int ix = redi[t][x];
        if (v < bv || (v == bv && ix < bi)) { bv = v; bi = ix; }
      }
      bidx[t] = bi;
      idxOut[(u64)(rowBase + t) * NQ + q] = (float)bi;   // np.argmin tie = smallest idx
    }
    __syncthreads();

    { // residual update + commit loss partial (loss_q = mean(new_residual^2))
      const int i = t >> 2, c0 = (t & 3) * 8;
      const float* crow = CBK + ((u64)q * CBN + bidx[i]) * DIM;
      float part = 0.f;
      #pragma unroll
      for (int c = c0; c < c0 + 8; ++c) {
        float rn = rs[i][c] - crow[c];
        rs[i][c] = rn;
        part = fmaf(rn, rn, part);
      }
      lred[t] = part;
    }
    __syncthreads();
    for (int s = 128; s > 0; s >>= 1) {
      if (t < s) lred[t] += lred[t + s];
      __syncthreads();
    }
    if (t == 0) atomicAdd(&lossAcc[q], lred[0]);
    __syncthreads();
  }

  // quant_out = z - final residual (straight-through forward value)
  for (int i = t; i < 64 * DIM; i += 256)
    Qout[(u64)rowBase * DIM + i] = zs[i >> 5][i & 31] - rs[i >> 5][i & 31];
}

__global__ void finalize_loss(const float* __restrict__ loss, float* __restrict__ out)
{
  if (threadIdx.x < NQ)
    out[threadIdx.x] = loss[threadIdx.x] * (1.0f / ((float)NR * (float)DIM));
}

extern "C" void kernel_launch(void* const* d_in, const int* in_sizes, int n_in,
                              void* d_out, int out_size, void* d_ws, size_t ws_size,
                              hipStream_t stream)
{
  const float* x   = (const float*)d_in[0];
  const float* ew0 = (const float*)d_in[1];
  const float* eb0 = (const float*)d_in[2];
  const float* ew1 = (const float*)d_in[3];
  const float* eb1 = (const float*)d_in[4];
  const float* ew2 = (const float*)d_in[5];
  const float* eb2 = (const float*)d_in[6];
  const float* cbk = (const float*)d_in[7];
  const float* dw0 = (const float*)d_in[8];
  const float* db0 = (const float*)d_in[9];
  const float* dw1 = (const float*)d_in[10];
  const float* db1 = (const float*)d_in[11];
  const float* dw2 = (const float*)d_in[12];
  const float* db2 = (const float*)d_in[13];

  float* ws   = (float*)d_ws;
  float* bufA = ws + OFF_A;     // h1, later dec-h2 [16384,512]
  float* bufB = ws + OFF_B;     // h2, later dec-h1 [16384,256]
  float* z    = ws + OFF_Z;
  float* qo   = ws + OFF_Q;
  float* cn   = ws + OFF_CN;
  float* loss = ws + OFF_LOSS;

  float* outf    = (float*)d_out;
  float* idxOut  = outf + IDX_OFF;
  float* lossOut = outf + LOSS_OFF;

  hipMemsetAsync(loss, 0, 4 * sizeof(float), stream);
  cnorm_kernel<<<(NQ * CBN + 255) / 256, 256, 0, stream>>>(cbk, cn);

  // encoder (f32 fidelity required for argmin correctness)
  sgemm128<true ><<<dim3(DD1 / 128, NR / 128), 256, 0, stream>>>(x,    ew0, eb0, bufA, NR, DD1, EMB);
  sgemm128<true ><<<dim3(DD2 / 128, NR / 128), 256, 0, stream>>>(bufA, ew1, eb1, bufB, NR, DD2, DD1);
  enc2_kernel<<<NR / 64, 256, 0, stream>>>(bufB, ew2, eb2, z);

  // residual VQ (indices + quant_out + commit-loss partials)
  vq_kernel<<<NR / 64, 256, 0, stream>>>(z, cbk, cn, qo, loss, idxOut);

  // decoder
  sgemm128<true ><<<dim3(DD2 / 128, NR / 128), 256, 0, stream>>>(qo,   dw0, db0, bufB, NR, DD2, DIM);
  sgemm128<true ><<<dim3(DD1 / 128, NR / 128), 256, 0, stream>>>(bufB, dw1, db1, bufA, NR, DD1, DD2);
  sgemm128<false><<<dim3(EMB / 128, NR / 128), 256, 0, stream>>>(bufA, dw2, db2, outf, NR, EMB, DD1);

  finalize_loss<<<1, 64, 0, stream>>>(loss, lossOut);
}